// Round 10
// baseline (14085.638 us; speedup 1.0000x reference)
//
#include <hip/hip_runtime.h>
#include <hip/hip_bf16.h>
#include <stdint.h>

// TiedEmbeddingLinear: out[8192, 32768] = x[8192,4096] . W^T
// Pass 1: dequant NF4 W -> bf16 (ws). Pass 2: x fp32 -> bf16 (ws).
// Pass 3: 256x256 bf16 NT-GEMM. R9/R10: B fragments read DIRECTLY from global
// (L2-resident panel) via asm global_load_dwordx4 + counted vmcnt; LDS holds
// A only (64 KiB) -> 2 blocks/CU (cross-block MFMA/read overlap, m114);
// ONE barrier per K-tile; wrapped A-stage (uniform vmcnt, no tail cases).
// R10 fix: XCD swizzle chunk = nwg/8 = 512 (R9 used 2048 -> wg up to 14847
// on a 4096-block grid -> OOB out-writes -> core dump).

#define M_DIM 8192
#define N_DIM 32768
#define K_DIM 4096
#define NT    64        // K / BK, BK = 64

typedef __attribute__((ext_vector_type(8))) short short8;
typedef __attribute__((ext_vector_type(4))) float f32x4;

__device__ __forceinline__ ushort f2bf(float f) {
    union { __hip_bfloat16 b; ushort u; } cv;
    cv.b = __float2bfloat16(f);
    return cv.u;
}

__device__ __forceinline__ void gload16(const ushort* g, ushort* l) {
    __builtin_amdgcn_global_load_lds(
        (const __attribute__((address_space(1))) unsigned int*)g,
        (__attribute__((address_space(3))) unsigned int*)l,
        16, 0, 0);
}

// asm LDS read (opaque to alias analysis; we own lgkmcnt)
__device__ __forceinline__ short8 ldsread128(const ushort* p) {
    short8 r;
    uint32_t a = (uint32_t)(uintptr_t)(const __attribute__((address_space(3))) ushort*)p;
    asm volatile("ds_read_b128 %0, %1" : "=v"(r) : "v"(a));
    return r;
}

// asm global read into regs (B fragments); "memory" pins program order vs
// the gload_lds builtins so the vmcnt FIFO counts are exact.
__device__ __forceinline__ short8 gread128(const ushort* p) {
    short8 r;
    asm volatile("global_load_dwordx4 %0, %1, off" : "=v"(r) : "v"(p) : "memory");
    return r;
}

#define BAR()     asm volatile("s_barrier" ::: "memory")
#define VMCNT(N)  do { asm volatile("s_waitcnt vmcnt(" #N ")" ::: "memory"); \
                       __builtin_amdgcn_sched_barrier(0); } while (0)
#define LGKM0()   do { asm volatile("s_waitcnt lgkmcnt(0)" ::: "memory"); \
                       __builtin_amdgcn_sched_barrier(0); } while (0)
#define SCHED0()  __builtin_amdgcn_sched_barrier(0)

// ---------------- pass 1: dequant W ----------------
__global__ __launch_bounds__(256) void dequant_w(
    const int* __restrict__ qw, const float* __restrict__ cb,
    uint32_t* __restrict__ wout)
{
    __shared__ uint32_t lut[256];
    const int tid = threadIdx.x;
    {
        const uint32_t h = f2bf(cb[(tid >> 4) & 15]);   // high nibble -> even d
        const uint32_t l = f2bf(cb[tid & 15]);          // low nibble  -> odd d
        lut[tid] = h | (l << 16);
    }
    __syncthreads();

    const size_t base = (size_t)blockIdx.x * 256 + tid;
    const int4* q4 = (const int4*)qw;
    uint4* w4 = (uint4*)wout;
    #pragma unroll
    for (int it = 0; it < 16; ++it) {
        const size_t idx = base + (size_t)it * (4096 * 256);
        const int4 q = q4[idx];
        uint4 w;
        w.x = lut[q.x & 255]; w.y = lut[q.y & 255];
        w.z = lut[q.z & 255]; w.w = lut[q.w & 255];
        w4[idx] = w;
    }
}

// ---------------- pass 2: x fp32 -> bf16 ----------------
__global__ __launch_bounds__(256) void conv_x(
    const float* __restrict__ x, ushort* __restrict__ xb)
{
    const size_t base = (size_t)blockIdx.x * 256 + threadIdx.x;
    #pragma unroll
    for (int it = 0; it < 8; ++it) {
        const size_t idx = (base + (size_t)it * (2048 * 256)) * 8;
        const float4 a = *(const float4*)(x + idx);
        const float4 b = *(const float4*)(x + idx + 4);
        short8 o;
        o[0] = f2bf(a.x); o[1] = f2bf(a.y); o[2] = f2bf(a.z); o[3] = f2bf(a.w);
        o[4] = f2bf(b.x); o[5] = f2bf(b.y); o[6] = f2bf(b.z); o[7] = f2bf(b.w);
        *(short8*)(xb + idx) = o;
    }
}

// ---------------- pass 3: 256^2 bf16 NT-GEMM, B-direct-from-L2 ----------
__global__ __launch_bounds__(512, 4) void gemm_bd(
    const ushort* __restrict__ xb, const ushort* __restrict__ wb,
    const float* __restrict__ absmax, float* __restrict__ out)
{
    __shared__ ushort smA[32768];   // 64 KiB: (buf*2+half)*8192 — A only

    const int tid  = threadIdx.x;
    const int lane = tid & 63;
    const int wv   = tid >> 6;      // 0..7
    const int wm   = wv >> 2;       // 0..1
    const int wn   = wv & 3;        // 0..3

    // bijective XCD-chunked swizzle: nwg = 4096, chunk = nwg/8 = 512.
    // Each XCD's resident blocks (~64) span <=2 consecutive B panels (4 MB = L2).
    const int bid = blockIdx.x;
    const int wg  = (bid & 7) * 512 + (bid >> 3);
    const int gm0 = (wg & 31) << 8;
    const int gn0 = (wg >> 5) << 8;

    const int l8    = lane >> 3;             // row within 8-row staging chunk
    const int sgran = (lane & 7) ^ l8;       // swizzled SOURCE granule (16B units)

    const ushort* aSrc = xb + (size_t)(gm0 + wv * 16 + l8) * K_DIM + sgran * 8;

    const int lr  = lane & 15;
    const int g   = lane >> 4;
    const int lr7 = lane & 7;

    // per-lane B base: row = gn0 + wn*64 + lr, k-granule g (8 bf16)
    const ushort* bgl = wb + (size_t)(gn0 + wn * 64 + lr) * K_DIM + g * 8;

    f32x4  acc[8][4] = {};
    short8 af[4][2], bf[4][2];

    #define LDFRAG(P, ROW, S) \
        ldsread128((P) + ((ROW) + lr) * 64 + ((((S) * 4 + g) ^ lr7) * 8))

    #define STAGE_A(TB, H, KT) do { \
        ushort* _d = smA + ((TB) * 2 + (H)) * 8192 + wv * 1024; \
        gload16(aSrc + (size_t)((H) * 128 + 0) * K_DIM + (KT) * 64, _d); \
        gload16(aSrc + (size_t)((H) * 128 + 8) * K_DIM + (KT) * 64, _d + 512); \
    } while (0)

    #define MFMAS(MB, NB) do { \
        __builtin_amdgcn_s_setprio(1); \
        _Pragma("unroll") \
        for (int m = 0; m < 4; ++m) \
            _Pragma("unroll") \
            for (int n = 0; n < 2; ++n) \
                _Pragma("unroll") \
                for (int s = 0; s < 2; ++s) \
                    acc[(MB) + m][(NB) + n] = __builtin_amdgcn_mfma_f32_16x16x32_bf16( \
                        af[m][s], bf[(NB) + n][s], acc[(MB) + m][(NB) + n], 0, 0, 0); \
        __builtin_amdgcn_s_setprio(0); \
    } while (0)

    // ---- prologue: stage A(0) -> buf0, drain, barrier ----
    STAGE_A(0, 0, 0); STAGE_A(0, 1, 0);
    VMCNT(0);
    BAR();

    for (int j = 0; j < NT; ++j) {
        const int buf = j & 1;
        const int jn  = (j + 1) & (NT - 1);          // wrapped: uniform counts, no tail
        const ushort* Ar = smA + (buf * 2 + wm) * 8192;
        const ushort* bk = bgl + j * 64;

        // ---- issue: af m0-3 (8 ds) | B n0-3 (8 vm, oldest) | stage A(j+1) (4 vm, newest) ----
        #pragma unroll
        for (int m = 0; m < 4; ++m) {
            af[m][0] = LDFRAG(Ar, m * 16, 0);
            af[m][1] = LDFRAG(Ar, m * 16, 1);
        }
        #pragma unroll
        for (int n = 0; n < 4; ++n) {
            bf[n][0] = gread128(bk + (size_t)n * 16 * K_DIM);
            bf[n][1] = gread128(bk + (size_t)n * 16 * K_DIM + 32);
        }
        SCHED0();
        STAGE_A(buf ^ 1, 0, jn);
        STAGE_A(buf ^ 1, 1, jn);

        // ---- consume ----
        LGKM0();            // af m0-3 resident
        VMCNT(8);           // bf n0-1 retired (A-stage 4 + bf n2-3 4 in flight)
        MFMAS(0, 0);        // Q1: m0-3 x n0-1

        VMCNT(4);           // bf n2-3 retired (A-stage 4 in flight)
        MFMAS(0, 2);        // Q2: m0-3 x n2-3

        #pragma unroll      // af m4-7 (WAR-safe: Q1/Q2 issued)
        for (int m = 0; m < 4; ++m) {
            af[m][0] = LDFRAG(Ar, (4 + m) * 16, 0);
            af[m][1] = LDFRAG(Ar, (4 + m) * 16, 1);
        }
        LGKM0();
        MFMAS(4, 0);        // Q3: m4-7 x n0-1
        MFMAS(4, 2);        // Q4: m4-7 x n2-3

        VMCNT(0);           // A(j+1) landed (issued ~full tile ago -> ~free)
        BAR();              // single barrier per K-tile: stage-retire + WAR
    }

    // ---- epilogue: absmax[col] scale, plain fp32 stores ----
    float am[4];
    #pragma unroll
    for (int n = 0; n < 4; ++n)
        am[n] = absmax[gn0 + wn * 64 + n * 16 + lr];

    const int row0 = gm0 + wm * 128 + g * 4;
    const int col0 = gn0 + wn * 64 + lr;
    #pragma unroll
    for (int m = 0; m < 8; ++m) {
        #pragma unroll
        for (int n = 0; n < 4; ++n) {
            #pragma unroll
            for (int r = 0; r < 4; ++r) {
                out[(size_t)(row0 + m * 16 + r) * N_DIM + col0 + n * 16] =
                    acc[m][n][r] * am[n];
            }
        }
    }
}

extern "C" void kernel_launch(void* const* d_in, const int* in_sizes, int n_in,
                              void* d_out, int out_size, void* d_ws, size_t ws_size,
                              hipStream_t stream) {
    const float* x      = (const float*)d_in[0];
    const int*   qw     = (const int*)d_in[1];
    const float* absmax = (const float*)d_in[2];
    const float* cb     = (const float*)d_in[3];
    float* out = (float*)d_out;

    const size_t W_BYTES = (size_t)N_DIM * K_DIM * 2;   // 256 MiB bf16 W
    uint32_t* wq  = (uint32_t*)d_ws;
    ushort*   xbf = (ushort*)((char*)d_ws + W_BYTES);

    dequant_w<<<4096, 256, 0, stream>>>(qw, cb, wq);
    conv_x<<<2048, 256, 0, stream>>>(x, xbf);
    gemm_bd<<<dim3((M_DIM / 256) * (N_DIM / 256)), dim3(512), 0, stream>>>(
        xbf, (const ushort*)wq, absmax, out);
}

// Round 11
// 3373.996 us; speedup vs baseline: 4.1748x; 4.1748x over previous
//
#include <hip/hip_runtime.h>
#include <hip/hip_bf16.h>
#include <stdint.h>

// TiedEmbeddingLinear: out[8192, 32768] = x[8192,4096] . W^T
// Pass 1: dequant NF4 W -> bf16 (ws). Pass 2: x fp32 -> bf16 (ws).
// Pass 3: 256x256 bf16 NT-GEMM. B fragments read DIRECTLY from global
// (L2/L1-resident panel) via asm global_load_dwordx4 + counted vmcnt; LDS
// holds A only (64 KiB); ONE barrier per K-tile; wrapped A-stage.
// R11 fix: __launch_bounds__(512, 2). R10's (512,4) capped the unified
// VGPR+AGPR budget at 128/wave; acc[8][4] alone needs 128 AGPR -> the
// allocator spilled accumulators to scratch (39 GB HBM writes, MfmaUtil 6.6%).
// 256 regs/wave fits the ~250 needed; occupancy 1 block/CU is acceptable —
// overlap comes from the counted-vmcnt schedule, not TLP.

#define M_DIM 8192
#define N_DIM 32768
#define K_DIM 4096
#define NT    64        // K / BK, BK = 64

typedef __attribute__((ext_vector_type(8))) short short8;
typedef __attribute__((ext_vector_type(4))) float f32x4;

__device__ __forceinline__ ushort f2bf(float f) {
    union { __hip_bfloat16 b; ushort u; } cv;
    cv.b = __float2bfloat16(f);
    return cv.u;
}

__device__ __forceinline__ void gload16(const ushort* g, ushort* l) {
    __builtin_amdgcn_global_load_lds(
        (const __attribute__((address_space(1))) unsigned int*)g,
        (__attribute__((address_space(3))) unsigned int*)l,
        16, 0, 0);
}

// asm LDS read (opaque to alias analysis; we own lgkmcnt)
__device__ __forceinline__ short8 ldsread128(const ushort* p) {
    short8 r;
    uint32_t a = (uint32_t)(uintptr_t)(const __attribute__((address_space(3))) ushort*)p;
    asm volatile("ds_read_b128 %0, %1" : "=v"(r) : "v"(a));
    return r;
}

// asm global read into regs (B fragments); "memory" pins program order vs
// the gload_lds builtins so the vmcnt FIFO counts are exact.
__device__ __forceinline__ short8 gread128(const ushort* p) {
    short8 r;
    asm volatile("global_load_dwordx4 %0, %1, off" : "=v"(r) : "v"(p) : "memory");
    return r;
}

#define BAR()     asm volatile("s_barrier" ::: "memory")
#define VMCNT(N)  do { asm volatile("s_waitcnt vmcnt(" #N ")" ::: "memory"); \
                       __builtin_amdgcn_sched_barrier(0); } while (0)
#define LGKM0()   do { asm volatile("s_waitcnt lgkmcnt(0)" ::: "memory"); \
                       __builtin_amdgcn_sched_barrier(0); } while (0)
#define SCHED0()  __builtin_amdgcn_sched_barrier(0)

// ---------------- pass 1: dequant W ----------------
__global__ __launch_bounds__(256) void dequant_w(
    const int* __restrict__ qw, const float* __restrict__ cb,
    uint32_t* __restrict__ wout)
{
    __shared__ uint32_t lut[256];
    const int tid = threadIdx.x;
    {
        const uint32_t h = f2bf(cb[(tid >> 4) & 15]);   // high nibble -> even d
        const uint32_t l = f2bf(cb[tid & 15]);          // low nibble  -> odd d
        lut[tid] = h | (l << 16);
    }
    __syncthreads();

    const size_t base = (size_t)blockIdx.x * 256 + tid;
    const int4* q4 = (const int4*)qw;
    uint4* w4 = (uint4*)wout;
    #pragma unroll
    for (int it = 0; it < 16; ++it) {
        const size_t idx = base + (size_t)it * (4096 * 256);
        const int4 q = q4[idx];
        uint4 w;
        w.x = lut[q.x & 255]; w.y = lut[q.y & 255];
        w.z = lut[q.z & 255]; w.w = lut[q.w & 255];
        w4[idx] = w;
    }
}

// ---------------- pass 2: x fp32 -> bf16 ----------------
__global__ __launch_bounds__(256) void conv_x(
    const float* __restrict__ x, ushort* __restrict__ xb)
{
    const size_t base = (size_t)blockIdx.x * 256 + threadIdx.x;
    #pragma unroll
    for (int it = 0; it < 8; ++it) {
        const size_t idx = (base + (size_t)it * (2048 * 256)) * 8;
        const float4 a = *(const float4*)(x + idx);
        const float4 b = *(const float4*)(x + idx + 4);
        short8 o;
        o[0] = f2bf(a.x); o[1] = f2bf(a.y); o[2] = f2bf(a.z); o[3] = f2bf(a.w);
        o[4] = f2bf(b.x); o[5] = f2bf(b.y); o[6] = f2bf(b.z); o[7] = f2bf(b.w);
        *(short8*)(xb + idx) = o;
    }
}

// ---------------- pass 3: 256^2 bf16 NT-GEMM, B-direct-from-L2 ----------
__global__ __launch_bounds__(512, 2) void gemm_bd(
    const ushort* __restrict__ xb, const ushort* __restrict__ wb,
    const float* __restrict__ absmax, float* __restrict__ out)
{
    __shared__ ushort smA[32768];   // 64 KiB: (buf*2+half)*8192 — A only

    const int tid  = threadIdx.x;
    const int lane = tid & 63;
    const int wv   = tid >> 6;      // 0..7
    const int wm   = wv >> 2;       // 0..1
    const int wn   = wv & 3;        // 0..3

    // bijective XCD-chunked swizzle: nwg = 4096, chunk = nwg/8 = 512.
    // Each XCD's resident blocks span <=2 consecutive B panels (4 MB = L2).
    const int bid = blockIdx.x;
    const int wg  = (bid & 7) * 512 + (bid >> 3);
    const int gm0 = (wg & 31) << 8;
    const int gn0 = (wg >> 5) << 8;

    const int l8    = lane >> 3;             // row within 8-row staging chunk
    const int sgran = (lane & 7) ^ l8;       // swizzled SOURCE granule (16B units)

    const ushort* aSrc = xb + (size_t)(gm0 + wv * 16 + l8) * K_DIM + sgran * 8;

    const int lr  = lane & 15;
    const int g   = lane >> 4;
    const int lr7 = lane & 7;

    // per-lane B base: row = gn0 + wn*64 + lr, k-granule g (8 bf16)
    const ushort* bgl = wb + (size_t)(gn0 + wn * 64 + lr) * K_DIM + g * 8;

    f32x4  acc[8][4] = {};
    short8 af[4][2], bf[4][2];

    #define LDFRAG(P, ROW, S) \
        ldsread128((P) + ((ROW) + lr) * 64 + ((((S) * 4 + g) ^ lr7) * 8))

    #define STAGE_A(TB, H, KT) do { \
        ushort* _d = smA + ((TB) * 2 + (H)) * 8192 + wv * 1024; \
        gload16(aSrc + (size_t)((H) * 128 + 0) * K_DIM + (KT) * 64, _d); \
        gload16(aSrc + (size_t)((H) * 128 + 8) * K_DIM + (KT) * 64, _d + 512); \
    } while (0)

    #define MFMAS(MB, NB) do { \
        __builtin_amdgcn_s_setprio(1); \
        _Pragma("unroll") \
        for (int m = 0; m < 4; ++m) \
            _Pragma("unroll") \
            for (int n = 0; n < 2; ++n) \
                _Pragma("unroll") \
                for (int s = 0; s < 2; ++s) \
                    acc[(MB) + m][(NB) + n] = __builtin_amdgcn_mfma_f32_16x16x32_bf16( \
                        af[m][s], bf[(NB) + n][s], acc[(MB) + m][(NB) + n], 0, 0, 0); \
        __builtin_amdgcn_s_setprio(0); \
    } while (0)

    // ---- prologue: stage A(0) -> buf0, drain, barrier ----
    STAGE_A(0, 0, 0); STAGE_A(0, 1, 0);
    VMCNT(0);
    BAR();

    for (int j = 0; j < NT; ++j) {
        const int buf = j & 1;
        const int jn  = (j + 1) & (NT - 1);          // wrapped: uniform counts, no tail
        const ushort* Ar = smA + (buf * 2 + wm) * 8192;
        const ushort* bk = bgl + j * 64;

        // ---- issue: af m0-3 (8 ds) | B n0-3 (8 vm, oldest) | stage A(j+1) (4 vm, newest) ----
        #pragma unroll
        for (int m = 0; m < 4; ++m) {
            af[m][0] = LDFRAG(Ar, m * 16, 0);
            af[m][1] = LDFRAG(Ar, m * 16, 1);
        }
        #pragma unroll
        for (int n = 0; n < 4; ++n) {
            bf[n][0] = gread128(bk + (size_t)n * 16 * K_DIM);
            bf[n][1] = gread128(bk + (size_t)n * 16 * K_DIM + 32);
        }
        SCHED0();
        STAGE_A(buf ^ 1, 0, jn);
        STAGE_A(buf ^ 1, 1, jn);

        // ---- consume ----
        LGKM0();            // af m0-3 resident
        VMCNT(8);           // bf n0-1 retired (A-stage 4 + bf n2-3 4 in flight)
        MFMAS(0, 0);        // Q1: m0-3 x n0-1

        VMCNT(4);           // bf n2-3 retired (A-stage 4 in flight)
        MFMAS(0, 2);        // Q2: m0-3 x n2-3

        #pragma unroll      // af m4-7 (WAR-safe: Q1/Q2 issued)
        for (int m = 0; m < 4; ++m) {
            af[m][0] = LDFRAG(Ar, (4 + m) * 16, 0);
            af[m][1] = LDFRAG(Ar, (4 + m) * 16, 1);
        }
        LGKM0();
        MFMAS(4, 0);        // Q3: m4-7 x n0-1
        MFMAS(4, 2);        // Q4: m4-7 x n2-3

        VMCNT(0);           // A(j+1) landed (issued ~full tile ago -> ~free)
        BAR();              // single barrier per K-tile: stage-retire + WAR
    }

    // ---- epilogue: absmax[col] scale, plain fp32 stores ----
    float am[4];
    #pragma unroll
    for (int n = 0; n < 4; ++n)
        am[n] = absmax[gn0 + wn * 64 + n * 16 + lr];

    const int row0 = gm0 + wm * 128 + g * 4;
    const int col0 = gn0 + wn * 64 + lr;
    #pragma unroll
    for (int m = 0; m < 8; ++m) {
        #pragma unroll
        for (int n = 0; n < 4; ++n) {
            #pragma unroll
            for (int r = 0; r < 4; ++r) {
                out[(size_t)(row0 + m * 16 + r) * N_DIM + col0 + n * 16] =
                    acc[m][n][r] * am[n];
            }
        }
    }
}

extern "C" void kernel_launch(void* const* d_in, const int* in_sizes, int n_in,
                              void* d_out, int out_size, void* d_ws, size_t ws_size,
                              hipStream_t stream) {
    const float* x      = (const float*)d_in[0];
    const int*   qw     = (const int*)d_in[1];
    const float* absmax = (const float*)d_in[2];
    const float* cb     = (const float*)d_in[3];
    float* out = (float*)d_out;

    const size_t W_BYTES = (size_t)N_DIM * K_DIM * 2;   // 256 MiB bf16 W
    uint32_t* wq  = (uint32_t*)d_ws;
    ushort*   xbf = (ushort*)((char*)d_ws + W_BYTES);

    dequant_w<<<4096, 256, 0, stream>>>(qw, cb, wq);
    conv_x<<<2048, 256, 0, stream>>>(x, xbf);
    gemm_bd<<<dim3((M_DIM / 256) * (N_DIM / 256)), dim3(512), 0, stream>>>(
        xbf, (const ushort*)wq, absmax, out);
}

// Round 12
// 2437.271 us; speedup vs baseline: 5.7793x; 1.3843x over previous
//
#include <hip/hip_runtime.h>
#include <hip/hip_bf16.h>
#include <stdint.h>

// TiedEmbeddingLinear: out[8192, 32768] = x[8192,4096] . W^T
// Pass 1: dequant NF4 W -> bf16 (ws). Pass 2: x fp32 -> bf16 (ws).
// Pass 3: 256x256 bf16 NT-GEMM, BK=32, CROSS-TILE READ PIPELINE:
// barrier at tile top; immediately issue tile j+1's fragment reads (legal:
// stage(j+1) retired by this barrier — R7 rule); MFMA tile j from registers
// loaded last tile. 4-deep LDS buffers (128 KiB), double register sets,
// counted lgkmcnt(12)/(8), single vmcnt(0)+barrier per tile. R11 lesson:
// B-direct-from-L2 exposes unhidden latency; both operands back in LDS.

#define M_DIM 8192
#define N_DIM 32768
#define K_DIM 4096
#define NT    128       // K / BK, BK = 32

typedef __attribute__((ext_vector_type(8))) short short8;
typedef __attribute__((ext_vector_type(4))) float f32x4;

__device__ __forceinline__ ushort f2bf(float f) {
    union { __hip_bfloat16 b; ushort u; } cv;
    cv.b = __float2bfloat16(f);
    return cv.u;
}

__device__ __forceinline__ void gload16(const ushort* g, ushort* l) {
    __builtin_amdgcn_global_load_lds(
        (const __attribute__((address_space(1))) unsigned int*)g,
        (__attribute__((address_space(3))) unsigned int*)l,
        16, 0, 0);
}

// asm LDS read (opaque to alias analysis; we own lgkmcnt)
__device__ __forceinline__ short8 ldsread128(const ushort* p) {
    short8 r;
    uint32_t a = (uint32_t)(uintptr_t)(const __attribute__((address_space(3))) ushort*)p;
    asm volatile("ds_read_b128 %0, %1" : "=v"(r) : "v"(a));
    return r;
}

#define BAR()     asm volatile("s_barrier" ::: "memory")
#define VMCNT0()  do { asm volatile("s_waitcnt vmcnt(0)" ::: "memory"); \
                       __builtin_amdgcn_sched_barrier(0); } while (0)
#define LGKM(N)   do { asm volatile("s_waitcnt lgkmcnt(" #N ")" ::: "memory"); \
                       __builtin_amdgcn_sched_barrier(0); } while (0)
#define SCHED0()  __builtin_amdgcn_sched_barrier(0)

// ---------------- pass 1: dequant W ----------------
__global__ __launch_bounds__(256) void dequant_w(
    const int* __restrict__ qw, const float* __restrict__ cb,
    uint32_t* __restrict__ wout)
{
    __shared__ uint32_t lut[256];
    const int tid = threadIdx.x;
    {
        const uint32_t h = f2bf(cb[(tid >> 4) & 15]);   // high nibble -> even d
        const uint32_t l = f2bf(cb[tid & 15]);          // low nibble  -> odd d
        lut[tid] = h | (l << 16);
    }
    __syncthreads();

    const size_t base = (size_t)blockIdx.x * 256 + tid;
    const int4* q4 = (const int4*)qw;
    uint4* w4 = (uint4*)wout;
    #pragma unroll
    for (int it = 0; it < 16; ++it) {
        const size_t idx = base + (size_t)it * (4096 * 256);
        const int4 q = q4[idx];
        uint4 w;
        w.x = lut[q.x & 255]; w.y = lut[q.y & 255];
        w.z = lut[q.z & 255]; w.w = lut[q.w & 255];
        w4[idx] = w;
    }
}

// ---------------- pass 2: x fp32 -> bf16 ----------------
__global__ __launch_bounds__(256) void conv_x(
    const float* __restrict__ x, ushort* __restrict__ xb)
{
    const size_t base = (size_t)blockIdx.x * 256 + threadIdx.x;
    #pragma unroll
    for (int it = 0; it < 8; ++it) {
        const size_t idx = (base + (size_t)it * (2048 * 256)) * 8;
        const float4 a = *(const float4*)(x + idx);
        const float4 b = *(const float4*)(x + idx + 4);
        short8 o;
        o[0] = f2bf(a.x); o[1] = f2bf(a.y); o[2] = f2bf(a.z); o[3] = f2bf(a.w);
        o[4] = f2bf(b.x); o[5] = f2bf(b.y); o[6] = f2bf(b.z); o[7] = f2bf(b.w);
        *(short8*)(xb + idx) = o;
    }
}

// ---------------- pass 3: 256^2 bf16 NT-GEMM, cross-tile pipelined ----------
__global__ __launch_bounds__(512, 2) void gemm_pl(
    const ushort* __restrict__ xb, const ushort* __restrict__ wb,
    const float* __restrict__ absmax, float* __restrict__ out)
{
    __shared__ ushort smA[4 * 8192];   // 64 KiB: 4 bufs x [256 rows][32 bf16]
    __shared__ ushort smB[4 * 8192];   // 64 KiB

    const int tid  = threadIdx.x;
    const int lane = tid & 63;
    const int wv   = tid >> 6;      // 0..7
    const int wm   = wv >> 2;       // 0..1  (128-row block)
    const int wn   = wv & 3;        // 0..3  (64-col block)

    const int bid = blockIdx.x;
    const int gm0 = (bid & 31) << 8;    // m fast: B panels shared, A L3-resident
    const int gn0 = (bid >> 5) << 8;

    // staging decomposition: 1 gload16 = 16 rows x 64B. lane -> (row, phys gran)
    const int rr = lane >> 2;                      // row within 16-row chunk
    const int pg = lane & 3;                       // phys 16B granule
    const int ks = (rr & 3) ^ ((rr >> 2) & 3);     // swizzle key (row-derived)
    const int sc = (pg ^ ks) * 8;                  // source col (ushorts)

    const ushort* aS = xb + (size_t)(gm0 + wv * 32 + rr) * K_DIM + sc;
    const ushort* bS = wb + (size_t)(gn0 + wv * 32 + rr) * K_DIM + sc;

    // fragment read decomposition (16x16x32, one k-slice per tile)
    const int lr = lane & 15;
    const int g  = lane >> 4;                      // logical granule
    const int kr = (lr & 3) ^ (lr >> 2);           // same key (ROW % 16 == 0)

    f32x4  acc[8][4] = {};
    short8 af0[4], bf0[4], af1[4], bf1[4], afh[4];

    // read logical granule g at LDS row (ROW+lr): phys gran = g ^ kr
    #define LDF(P, ROW) ldsread128((P) + ((ROW) + lr) * 32 + (((g) ^ kr) * 8))

    #define STAGE(TB, KT) do { \
        ushort* _da = (ushort*)smA + (TB) * 8192 + wv * 1024; \
        ushort* _db = (ushort*)smB + (TB) * 8192 + wv * 1024; \
        gload16(aS + (size_t)(KT) * 32, _da); \
        gload16(aS + (size_t)(KT) * 32 + (size_t)16 * K_DIM, _da + 512); \
        gload16(bS + (size_t)(KT) * 32, _db); \
        gload16(bS + (size_t)(KT) * 32 + (size_t)16 * K_DIM, _db + 512); \
    } while (0)

    #define MFMAS_LO(AF, BF) do { \
        __builtin_amdgcn_s_setprio(1); \
        _Pragma("unroll") \
        for (int m = 0; m < 4; ++m) \
            _Pragma("unroll") \
            for (int n = 0; n < 4; ++n) \
                acc[m][n] = __builtin_amdgcn_mfma_f32_16x16x32_bf16( \
                    AF[m], BF[n], acc[m][n], 0, 0, 0); \
        __builtin_amdgcn_s_setprio(0); \
    } while (0)

    #define MFMAS_HI(BF) do { \
        __builtin_amdgcn_s_setprio(1); \
        _Pragma("unroll") \
        for (int m = 0; m < 4; ++m) \
            _Pragma("unroll") \
            for (int n = 0; n < 4; ++n) \
                acc[4 + m][n] = __builtin_amdgcn_mfma_f32_16x16x32_bf16( \
                    afh[m], BF[n], acc[4 + m][n], 0, 0, 0); \
        __builtin_amdgcn_s_setprio(0); \
    } while (0)

    // Tile J: BAR (stage(J+1) visible) | issue afh(J) m4-7 (4 ds, oldest) |
    // issue next set: A m0-3 + B n0-3 of J+1 (8 ds) | stage(J+2) (4 vm) |
    // lgkm(12): cur-set resident (retires leftover R_J) -> Q-lo |
    // lgkm(8): afh resident -> Q-hi | vmcnt(0): stage(J+2) landed | next BAR.
    #define TILE(J, AFC, BFC, AFN, BFN, BJ) do { \
        BAR(); \
        const ushort* _Ab = (const ushort*)smA + (BJ) * 8192; \
        const ushort* _Bb = (const ushort*)smB + (BJ) * 8192; \
        const ushort* _An = (const ushort*)smA + (((BJ) + 1) & 3) * 8192; \
        const ushort* _Bn = (const ushort*)smB + (((BJ) + 1) & 3) * 8192; \
        _Pragma("unroll") \
        for (int m = 0; m < 4; ++m) \
            afh[m] = LDF(_Ab, wm * 128 + 64 + m * 16); \
        _Pragma("unroll") \
        for (int m = 0; m < 4; ++m) \
            AFN[m] = LDF(_An, wm * 128 + m * 16); \
        _Pragma("unroll") \
        for (int n = 0; n < 4; ++n) \
            BFN[n] = LDF(_Bn, wn * 64 + n * 16); \
        STAGE((((BJ) + 2) & 3), (((J) + 2) & (NT - 1))); \
        LGKM(12); \
        MFMAS_LO(AFC, BFC); \
        LGKM(8); \
        MFMAS_HI(BFC); \
        VMCNT0(); \
    } while (0)

    // ---- prologue: stage tiles 0,1 -> buf0,buf1; load R_0 into set0 ----
    STAGE(0, 0);
    STAGE(1, 1);
    VMCNT0();
    BAR();
    #pragma unroll
    for (int m = 0; m < 4; ++m)
        af0[m] = LDF((const ushort*)smA, wm * 128 + m * 16);
    #pragma unroll
    for (int n = 0; n < 4; ++n)
        bf0[n] = LDF((const ushort*)smB, wn * 64 + n * 16);

    for (int j = 0; j < NT; j += 4) {
        TILE(j + 0, af0, bf0, af1, bf1, 0);
        TILE(j + 1, af1, bf1, af0, bf0, 1);
        TILE(j + 2, af0, bf0, af1, bf1, 2);
        TILE(j + 3, af1, bf1, af0, bf0, 3);
    }

    // ---- epilogue: absmax[col] scale, plain fp32 stores ----
    float am[4];
    #pragma unroll
    for (int n = 0; n < 4; ++n)
        am[n] = absmax[gn0 + wn * 64 + n * 16 + lr];

    const int row0 = gm0 + wm * 128 + g * 4;
    const int col0 = gn0 + wn * 64 + lr;
    #pragma unroll
    for (int m = 0; m < 8; ++m) {
        #pragma unroll
        for (int n = 0; n < 4; ++n) {
            #pragma unroll
            for (int r = 0; r < 4; ++r) {
                out[(size_t)(row0 + m * 16 + r) * N_DIM + col0 + n * 16] =
                    acc[m][n][r] * am[n];
            }
        }
    }
}

extern "C" void kernel_launch(void* const* d_in, const int* in_sizes, int n_in,
                              void* d_out, int out_size, void* d_ws, size_t ws_size,
                              hipStream_t stream) {
    const float* x      = (const float*)d_in[0];
    const int*   qw     = (const int*)d_in[1];
    const float* absmax = (const float*)d_in[2];
    const float* cb     = (const float*)d_in[3];
    float* out = (float*)d_out;

    const size_t W_BYTES = (size_t)N_DIM * K_DIM * 2;   // 256 MiB bf16 W
    uint32_t* wq  = (uint32_t*)d_ws;
    ushort*   xbf = (ushort*)((char*)d_ws + W_BYTES);

    dequant_w<<<4096, 256, 0, stream>>>(qw, cb, wq);
    conv_x<<<2048, 256, 0, stream>>>(x, xbf);
    gemm_pl<<<dim3((M_DIM / 256) * (N_DIM / 256)), dim3(512), 0, stream>>>(
        xbf, (const ushort*)wq, absmax, out);
}

// Round 13
// 1877.158 us; speedup vs baseline: 7.5037x; 1.2984x over previous
//
#include <hip/hip_runtime.h>
#include <hip/hip_bf16.h>
#include <stdint.h>

// TiedEmbeddingLinear: out[8192, 32768] = x[8192,4096] . W^T
// Pass 1: dequant NF4 W -> bf16 (ws). Pass 2: x fp32 -> bf16 (ws).
// Pass 3: 256x256 bf16 NT-GEMM, BK=64, PROVEN R5/R8 LDS geometry (128B rows,
// key=lane&7, granule (s*4+g)^lr7 -> 0 bank conflicts, measured twice).
// R13: cross-tile pipeline via asymmetric LDS depth: A 2-deep + B 3-deep
// = 160 KiB. bf(j+1) issued at END of tile j (queue-head across barrier);
// af read in 2-row pieces with counted LGKM(4/8) and issue-after-consume
// register rolling. One barrier + VMCNT(0) per tile (stages have full tile
// to land). All cross-wave WARs barrier-separated (R7 rule).

#define M_DIM 8192
#define N_DIM 32768
#define K_DIM 4096
#define NT    64        // K / BK, BK = 64

typedef __attribute__((ext_vector_type(8))) short short8;
typedef __attribute__((ext_vector_type(4))) float f32x4;

__device__ __forceinline__ ushort f2bf(float f) {
    union { __hip_bfloat16 b; ushort u; } cv;
    cv.b = __float2bfloat16(f);
    return cv.u;
}

__device__ __forceinline__ void gload16(const ushort* g, ushort* l) {
    __builtin_amdgcn_global_load_lds(
        (const __attribute__((address_space(1))) unsigned int*)g,
        (__attribute__((address_space(3))) unsigned int*)l,
        16, 0, 0);
}

// asm LDS read (opaque to alias analysis; we own lgkmcnt)
__device__ __forceinline__ short8 ldsread128(const ushort* p) {
    short8 r;
    uint32_t a = (uint32_t)(uintptr_t)(const __attribute__((address_space(3))) ushort*)p;
    asm volatile("ds_read_b128 %0, %1" : "=v"(r) : "v"(a));
    return r;
}

#define BAR()     asm volatile("s_barrier" ::: "memory")
#define VMCNT0()  do { asm volatile("s_waitcnt vmcnt(0)" ::: "memory"); \
                       __builtin_amdgcn_sched_barrier(0); } while (0)
#define LGKM(N)   do { asm volatile("s_waitcnt lgkmcnt(" #N ")" ::: "memory"); \
                       __builtin_amdgcn_sched_barrier(0); } while (0)

// ---------------- pass 1: dequant W ----------------
__global__ __launch_bounds__(256) void dequant_w(
    const int* __restrict__ qw, const float* __restrict__ cb,
    uint32_t* __restrict__ wout)
{
    __shared__ uint32_t lut[256];
    const int tid = threadIdx.x;
    {
        const uint32_t h = f2bf(cb[(tid >> 4) & 15]);   // high nibble -> even d
        const uint32_t l = f2bf(cb[tid & 15]);          // low nibble  -> odd d
        lut[tid] = h | (l << 16);
    }
    __syncthreads();

    const size_t base = (size_t)blockIdx.x * 256 + tid;
    const int4* q4 = (const int4*)qw;
    uint4* w4 = (uint4*)wout;
    #pragma unroll
    for (int it = 0; it < 16; ++it) {
        const size_t idx = base + (size_t)it * (4096 * 256);
        const int4 q = q4[idx];
        uint4 w;
        w.x = lut[q.x & 255]; w.y = lut[q.y & 255];
        w.z = lut[q.z & 255]; w.w = lut[q.w & 255];
        w4[idx] = w;
    }
}

// ---------------- pass 2: x fp32 -> bf16 ----------------
__global__ __launch_bounds__(256) void conv_x(
    const float* __restrict__ x, ushort* __restrict__ xb)
{
    const size_t base = (size_t)blockIdx.x * 256 + threadIdx.x;
    #pragma unroll
    for (int it = 0; it < 8; ++it) {
        const size_t idx = (base + (size_t)it * (2048 * 256)) * 8;
        const float4 a = *(const float4*)(x + idx);
        const float4 b = *(const float4*)(x + idx + 4);
        short8 o;
        o[0] = f2bf(a.x); o[1] = f2bf(a.y); o[2] = f2bf(a.z); o[3] = f2bf(a.w);
        o[4] = f2bf(b.x); o[5] = f2bf(b.y); o[6] = f2bf(b.z); o[7] = f2bf(b.w);
        *(short8*)(xb + idx) = o;
    }
}

// ---------------- pass 3: 256^2 bf16 NT-GEMM, A2/B3-deep pipeline ----------
__global__ __launch_bounds__(512, 2) void gemm_p3(
    const ushort* __restrict__ xb, const ushort* __restrict__ wb,
    const float* __restrict__ absmax, float* __restrict__ out)
{
    __shared__ ushort smA[2 * 16384];   // 64 KiB: 2 bufs x [256 rows][64 bf16]
    __shared__ ushort smB[3 * 16384];   // 96 KiB: 3 bufs

    const int tid  = threadIdx.x;
    const int lane = tid & 63;
    const int wv   = tid >> 6;      // 0..7
    const int wm   = wv >> 2;       // 0..1  (128-row block)
    const int wn   = wv & 3;        // 0..3  (64-col block)

    const int bid = blockIdx.x;
    const int gm0 = (bid & 31) << 8;    // m fast: B panels shared, A L3-resident
    const int gn0 = (bid >> 5) << 8;

    // staging (R8 exact): lane -> (row l8, swizzled source granule)
    const int l8    = lane >> 3;
    const int sgran = (lane & 7) ^ l8;

    const ushort* aSrc = xb + (size_t)(gm0 + wv * 16 + l8) * K_DIM + sgran * 8;
    const ushort* bSrc = wb + (size_t)(gn0 + wv * 16 + l8) * K_DIM + sgran * 8;

    const int lr  = lane & 15;
    const int g   = lane >> 4;
    const int lr7 = lane & 7;

    f32x4  acc[8][4] = {};
    short8 afA[2][2], afB[2][2];    // rolling af pieces: [m-pair][slice]
    short8 bfP[4][2], bfQ[4][2];    // ping-pong B sets

    #define LDF(P, ROW, S) \
        ldsread128((P) + ((ROW) + lr) * 64 + ((((S) * 4 + g) ^ lr7) * 8))

    // stage one 128-row half of a 256x64 tile (2 gload16); full tile = H0+H1
    #define STAGE(SRC, DST, KT) do { \
        gload16((SRC) + (size_t)(KT) * 64,                        (DST) + wv * 1024); \
        gload16((SRC) + (size_t)(KT) * 64 + (size_t)8 * K_DIM,    (DST) + wv * 1024 + 512); \
    } while (0)
    #define STAGE_T(SRC, DSTBASE, KT) do { \
        STAGE(SRC, DSTBASE, KT); \
        STAGE(SRC + (size_t)128 * K_DIM, (DSTBASE) + 8192, KT); \
    } while (0)

    // one quadrant: 2 m-rows x 4 n x 2 slices = 16 MFMA (s outer, n inner)
    #define MF16(AF, MB, BF) do { \
        __builtin_amdgcn_s_setprio(1); \
        _Pragma("unroll") \
        for (int s = 0; s < 2; ++s) \
            _Pragma("unroll") \
            for (int m2 = 0; m2 < 2; ++m2) \
                _Pragma("unroll") \
                for (int n = 0; n < 4; ++n) \
                    acc[(MB) + m2][n] = __builtin_amdgcn_mfma_f32_16x16x32_bf16( \
                        AF[m2][s], BF[n][s], acc[(MB) + m2][n], 0, 0, 0); \
        __builtin_amdgcn_s_setprio(0); \
    } while (0)

    #define RD_AF(SET, AB, MB) do { \
        _Pragma("unroll") \
        for (int m2 = 0; m2 < 2; ++m2) { \
            SET[m2][0] = LDF(AB, wm * 128 + ((MB) + m2) * 16, 0); \
            SET[m2][1] = LDF(AB, wm * 128 + ((MB) + m2) * 16, 1); \
        } \
    } while (0)
    #define RD_BF(SET, BB) do { \
        _Pragma("unroll") \
        for (int n = 0; n < 4; ++n) { \
            SET[n][0] = LDF(BB, wn * 64 + n * 16, 0); \
            SET[n][1] = LDF(BB, wn * 64 + n * 16, 1); \
        } \
    } while (0)

    // rotating B buffer offsets (ushort units): b0=B(j), b1=B(j+1), b2=B(j+2)
    int b0 = 0, b1 = 16384, b2 = 32768;

    // Tile body. Entry: BFC (bf of tile j) issued end of last tile (8 ds in
    // FIFO, queue-head); afA/afB free. ABASE = (j&1)*16384 (compile-time).
    // FIFO ledger: [bfc 8] +af0(4) +af1(4); LGKM(4)->bfc+af0; Q0; issue af2
    // into afA; LGKM(4)->af1; Q1; issue af3 into afB; LGKM(4)->af2; Q2;
    // issue bfn(8); LGKM(8)->af3; Q3; VMCNT(0); BAR. Leaves [bfn 8].
    #define TILE(J, ABASE, BFC, BFN) do { \
        const ushort* Ab = (const ushort*)smA + (ABASE); \
        const ushort* Bb = (const ushort*)smB + b0; \
        const ushort* Bn = (const ushort*)smB + b1; \
        RD_AF(afA, Ab, 0); \
        RD_AF(afB, Ab, 2); \
        STAGE_T(aSrc, (ushort*)smA + ((ABASE) ^ 16384), (((J) + 1) & (NT - 1))); \
        STAGE_T(bSrc, (ushort*)smB + b2,                (((J) + 2) & (NT - 1))); \
        LGKM(4);  MF16(afA, 0, BFC); \
        RD_AF(afA, Ab, 4); \
        LGKM(4);  MF16(afB, 2, BFC); \
        RD_AF(afB, Ab, 6); \
        LGKM(4);  MF16(afA, 4, BFC); \
        RD_BF(BFN, Bn); \
        LGKM(8);  MF16(afB, 6, BFC); \
        VMCNT0(); \
        BAR(); \
        int _t = b0; b0 = b1; b1 = b2; b2 = _t; \
    } while (0)

    // ---- prologue: stage A(0), B(0), B(1); issue bf(0) ----
    STAGE_T(aSrc, (ushort*)smA, 0);
    STAGE_T(bSrc, (ushort*)smB, 0);
    STAGE_T(bSrc, (ushort*)smB + 16384, 1);
    VMCNT0();
    BAR();
    RD_BF(bfP, (const ushort*)smB);   // FIFO: [bfP 8] — matches tile entry state

    for (int j = 0; j < NT; j += 2) {
        TILE(j,     0,     bfP, bfQ);
        TILE(j + 1, 16384, bfQ, bfP);
    }
    LGKM(0);   // retire trailing bf reads before epilogue reuses their regs

    // ---- epilogue: absmax[col] scale, plain fp32 stores ----
    float am[4];
    #pragma unroll
    for (int n = 0; n < 4; ++n)
        am[n] = absmax[gn0 + wn * 64 + n * 16 + lr];

    const int row0 = gm0 + wm * 128 + g * 4;
    const int col0 = gn0 + wn * 64 + lr;
    #pragma unroll
    for (int m = 0; m < 8; ++m) {
        #pragma unroll
        for (int n = 0; n < 4; ++n) {
            #pragma unroll
            for (int r = 0; r < 4; ++r) {
                out[(size_t)(row0 + m * 16 + r) * N_DIM + col0 + n * 16] =
                    acc[m][n][r] * am[n];
            }
        }
    }
}

extern "C" void kernel_launch(void* const* d_in, const int* in_sizes, int n_in,
                              void* d_out, int out_size, void* d_ws, size_t ws_size,
                              hipStream_t stream) {
    const float* x      = (const float*)d_in[0];
    const int*   qw     = (const int*)d_in[1];
    const float* absmax = (const float*)d_in[2];
    const float* cb     = (const float*)d_in[3];
    float* out = (float*)d_out;

    const size_t W_BYTES = (size_t)N_DIM * K_DIM * 2;   // 256 MiB bf16 W
    uint32_t* wq  = (uint32_t*)d_ws;
    ushort*   xbf = (ushort*)((char*)d_ws + W_BYTES);

    dequant_w<<<4096, 256, 0, stream>>>(qw, cb, wq);
    conv_x<<<2048, 256, 0, stream>>>(x, xbf);
    gemm_p3<<<dim3((M_DIM / 256) * (N_DIM / 256)), dim3(512), 0, stream>>>(
        xbf, (const ushort*)wq, absmax, out);
}

// Round 14
// 1877.098 us; speedup vs baseline: 7.5039x; 1.0000x over previous
//
#include <hip/hip_runtime.h>
#include <hip/hip_bf16.h>
#include <stdint.h>

// TiedEmbeddingLinear: out[8192, 32768] = x[8192,4096] . W^T
// Pass 1: dequant NF4 W -> bf16 (ws). Pass 2: x fp32 -> bf16 (ws).
// Pass 3: 256x256 bf16 NT-GEMM, BK=64, frozen R5/R8 LDS geometry (0 bank
// conflicts, measured 3x). A 2-deep + B 3-deep LDS (160 KiB), bf(j+1)
// issued end-of-tile-j, af rolling pieces with counted LGKM (R13).
// R14: WAVE-STAGGERED quadrant order — wm=1 waves (the SIMD-partners of
// wm=0 waves under wv%4 mapping) run Q2,Q3,Q0,Q1 with rotated af reads,
// halving the tile-top LDS burst and interleaving read/MFMA phases across
// waves. Pure rename per wave: FIFO ledger, staging, barriers identical.

#define M_DIM 8192
#define N_DIM 32768
#define K_DIM 4096
#define NT    64        // K / BK, BK = 64

typedef __attribute__((ext_vector_type(8))) short short8;
typedef __attribute__((ext_vector_type(4))) float f32x4;

__device__ __forceinline__ ushort f2bf(float f) {
    union { __hip_bfloat16 b; ushort u; } cv;
    cv.b = __float2bfloat16(f);
    return cv.u;
}

__device__ __forceinline__ void gload16(const ushort* g, ushort* l) {
    __builtin_amdgcn_global_load_lds(
        (const __attribute__((address_space(1))) unsigned int*)g,
        (__attribute__((address_space(3))) unsigned int*)l,
        16, 0, 0);
}

// asm LDS read (opaque to alias analysis; we own lgkmcnt)
__device__ __forceinline__ short8 ldsread128(const ushort* p) {
    short8 r;
    uint32_t a = (uint32_t)(uintptr_t)(const __attribute__((address_space(3))) ushort*)p;
    asm volatile("ds_read_b128 %0, %1" : "=v"(r) : "v"(a));
    return r;
}

#define BAR()     asm volatile("s_barrier" ::: "memory")
#define VMCNT0()  do { asm volatile("s_waitcnt vmcnt(0)" ::: "memory"); \
                       __builtin_amdgcn_sched_barrier(0); } while (0)
#define LGKM(N)   do { asm volatile("s_waitcnt lgkmcnt(" #N ")" ::: "memory"); \
                       __builtin_amdgcn_sched_barrier(0); } while (0)

// ---------------- pass 1: dequant W ----------------
__global__ __launch_bounds__(256) void dequant_w(
    const int* __restrict__ qw, const float* __restrict__ cb,
    uint32_t* __restrict__ wout)
{
    __shared__ uint32_t lut[256];
    const int tid = threadIdx.x;
    {
        const uint32_t h = f2bf(cb[(tid >> 4) & 15]);   // high nibble -> even d
        const uint32_t l = f2bf(cb[tid & 15]);          // low nibble  -> odd d
        lut[tid] = h | (l << 16);
    }
    __syncthreads();

    const size_t base = (size_t)blockIdx.x * 256 + tid;
    const int4* q4 = (const int4*)qw;
    uint4* w4 = (uint4*)wout;
    #pragma unroll
    for (int it = 0; it < 16; ++it) {
        const size_t idx = base + (size_t)it * (4096 * 256);
        const int4 q = q4[idx];
        uint4 w;
        w.x = lut[q.x & 255]; w.y = lut[q.y & 255];
        w.z = lut[q.z & 255]; w.w = lut[q.w & 255];
        w4[idx] = w;
    }
}

// ---------------- pass 2: x fp32 -> bf16 ----------------
__global__ __launch_bounds__(256) void conv_x(
    const float* __restrict__ x, ushort* __restrict__ xb)
{
    const size_t base = (size_t)blockIdx.x * 256 + threadIdx.x;
    #pragma unroll
    for (int it = 0; it < 8; ++it) {
        const size_t idx = (base + (size_t)it * (2048 * 256)) * 8;
        const float4 a = *(const float4*)(x + idx);
        const float4 b = *(const float4*)(x + idx + 4);
        short8 o;
        o[0] = f2bf(a.x); o[1] = f2bf(a.y); o[2] = f2bf(a.z); o[3] = f2bf(a.w);
        o[4] = f2bf(b.x); o[5] = f2bf(b.y); o[6] = f2bf(b.z); o[7] = f2bf(b.w);
        *(short8*)(xb + idx) = o;
    }
}

// ---------------- pass 3: 256^2 bf16 NT-GEMM, staggered A2/B3 pipeline ------
__global__ __launch_bounds__(512, 2) void gemm_p4(
    const ushort* __restrict__ xb, const ushort* __restrict__ wb,
    const float* __restrict__ absmax, float* __restrict__ out)
{
    __shared__ ushort smA[2 * 16384];   // 64 KiB
    __shared__ ushort smB[3 * 16384];   // 96 KiB

    const int tid  = threadIdx.x;
    const int lane = tid & 63;
    const int wv   = tid >> 6;      // 0..7
    const int wm   = wv >> 2;       // 0..1  (also the stagger group)
    const int wn   = wv & 3;        // 0..3

    const int bid = blockIdx.x;
    const int gm0 = (bid & 31) << 8;
    const int gn0 = (bid >> 5) << 8;

    // staging (R8 exact): lane -> (row l8, swizzled source granule)
    const int l8    = lane >> 3;
    const int sgran = (lane & 7) ^ l8;

    const ushort* aSrc = xb + (size_t)(gm0 + wv * 16 + l8) * K_DIM + sgran * 8;
    const ushort* bSrc = wb + (size_t)(gn0 + wv * 16 + l8) * K_DIM + sgran * 8;

    const int lr  = lane & 15;
    const int g   = lane >> 4;
    const int lr7 = lane & 7;

    f32x4  acc[8][4] = {};
    short8 afA[2][2], afB[2][2];    // rolling af pieces
    short8 bfP[4][2], bfQ[4][2];    // ping-pong B sets

    #define LDF(P, ROW, S) \
        ldsread128((P) + ((ROW) + lr) * 64 + ((((S) * 4 + g) ^ lr7) * 8))

    #define STAGE(SRC, DST, KT) do { \
        gload16((SRC) + (size_t)(KT) * 64,                     (DST) + wv * 1024); \
        gload16((SRC) + (size_t)(KT) * 64 + (size_t)8 * K_DIM, (DST) + wv * 1024 + 512); \
    } while (0)
    #define STAGE_T(SRC, DSTBASE, KT) do { \
        STAGE(SRC, DSTBASE, KT); \
        STAGE(SRC + (size_t)128 * K_DIM, (DSTBASE) + 8192, KT); \
    } while (0)

    // one quadrant: 2 m-rows x 4 n x 2 slices = 16 MFMA (MB literal)
    #define MF16(AF, MB, BF) do { \
        __builtin_amdgcn_s_setprio(1); \
        _Pragma("unroll") \
        for (int s = 0; s < 2; ++s) \
            _Pragma("unroll") \
            for (int m2 = 0; m2 < 2; ++m2) \
                _Pragma("unroll") \
                for (int n = 0; n < 4; ++n) \
                    acc[(MB) + m2][n] = __builtin_amdgcn_mfma_f32_16x16x32_bf16( \
                        AF[m2][s], BF[n][s], acc[(MB) + m2][n], 0, 0, 0); \
        __builtin_amdgcn_s_setprio(0); \
    } while (0)

    #define RD_AF(SET, AB, MB) do { \
        _Pragma("unroll") \
        for (int m2 = 0; m2 < 2; ++m2) { \
            SET[m2][0] = LDF(AB, wm * 128 + ((MB) + m2) * 16, 0); \
            SET[m2][1] = LDF(AB, wm * 128 + ((MB) + m2) * 16, 1); \
        } \
    } while (0)
    #define RD_BF(SET, BB) do { \
        _Pragma("unroll") \
        for (int n = 0; n < 4; ++n) { \
            SET[n][0] = LDF(BB, wn * 64 + n * 16, 0); \
            SET[n][1] = LDF(BB, wn * 64 + n * 16, 1); \
        } \
    } while (0)

    // Tile body, quadrant order (M0,M1,M2,M3) as literals.
    // FIFO ledger (per wave, identical for both orders):
    // entry [bfc 8]; +p0(4)+p1(4); LGKM(4)->bfc+p0; Q(M0); +p2; LGKM(4)->p1;
    // Q(M1); +p3; LGKM(4)->p2; Q(M2); +bfn(8); LGKM(8)->p3; Q(M3);
    // VMCNT0; BAR. Exit FIFO [bfn 8].
    #define TILE(J, ABASE, BFC, BFN, M0, M1, M2, M3) do { \
        const ushort* Ab = (const ushort*)smA + (ABASE); \
        const ushort* Bn = (const ushort*)smB + b1; \
        RD_AF(afA, Ab, M0); \
        RD_AF(afB, Ab, M1); \
        STAGE_T(aSrc, (ushort*)smA + ((ABASE) ^ 16384), (((J) + 1) & (NT - 1))); \
        STAGE_T(bSrc, (ushort*)smB + b2,                (((J) + 2) & (NT - 1))); \
        LGKM(4);  MF16(afA, M0, BFC); \
        RD_AF(afA, Ab, M2); \
        LGKM(4);  MF16(afB, M1, BFC); \
        RD_AF(afB, Ab, M3); \
        LGKM(4);  MF16(afA, M2, BFC); \
        RD_BF(BFN, Bn); \
        LGKM(8);  MF16(afB, M3, BFC); \
        VMCNT0(); \
        BAR(); \
        int _t = b0; b0 = b1; b1 = b2; b2 = _t; \
    } while (0)

    int b0 = 0, b1 = 16384, b2 = 32768;

    // ---- prologue: stage A(0), B(0), B(1); issue bf(0) ----
    STAGE_T(aSrc, (ushort*)smA, 0);
    STAGE_T(bSrc, (ushort*)smB, 0);
    STAGE_T(bSrc, (ushort*)smB + 16384, 1);
    VMCNT0();
    BAR();
    RD_BF(bfP, (const ushort*)smB);   // FIFO: [bfP 8] — matches tile entry state

    if (wm == 0) {
        for (int j = 0; j < NT; j += 2) {
            TILE(j,     0,     bfP, bfQ, 0, 2, 4, 6);
            TILE(j + 1, 16384, bfQ, bfP, 0, 2, 4, 6);
        }
    } else {
        // staggered: SIMD partner waves start at the m4-7 half
        for (int j = 0; j < NT; j += 2) {
            TILE(j,     0,     bfP, bfQ, 4, 6, 0, 2);
            TILE(j + 1, 16384, bfQ, bfP, 4, 6, 0, 2);
        }
    }
    LGKM(0);   // retire trailing bf reads before epilogue reuses their regs

    // ---- epilogue: absmax[col] scale, plain fp32 stores ----
    float am[4];
    #pragma unroll
    for (int n = 0; n < 4; ++n)
        am[n] = absmax[gn0 + wn * 64 + n * 16 + lr];

    const int row0 = gm0 + wm * 128 + g * 4;
    const int col0 = gn0 + wn * 64 + lr;
    #pragma unroll
    for (int m = 0; m < 8; ++m) {
        #pragma unroll
        for (int n = 0; n < 4; ++n) {
            #pragma unroll
            for (int r = 0; r < 4; ++r) {
                out[(size_t)(row0 + m * 16 + r) * N_DIM + col0 + n * 16] =
                    acc[m][n][r] * am[n];
            }
        }
    }
}

extern "C" void kernel_launch(void* const* d_in, const int* in_sizes, int n_in,
                              void* d_out, int out_size, void* d_ws, size_t ws_size,
                              hipStream_t stream) {
    const float* x      = (const float*)d_in[0];
    const int*   qw     = (const int*)d_in[1];
    const float* absmax = (const float*)d_in[2];
    const float* cb     = (const float*)d_in[3];
    float* out = (float*)d_out;

    const size_t W_BYTES = (size_t)N_DIM * K_DIM * 2;   // 256 MiB bf16 W
    uint32_t* wq  = (uint32_t*)d_ws;
    ushort*   xbf = (ushort*)((char*)d_ws + W_BYTES);

    dequant_w<<<4096, 256, 0, stream>>>(qw, cb, wq);
    conv_x<<<2048, 256, 0, stream>>>(x, xbf);
    gemm_p4<<<dim3((M_DIM / 256) * (N_DIM / 256)), dim3(512), 0, stream>>>(
        xbf, (const ushort*)wq, absmax, out);
}

// Round 15
// 1875.579 us; speedup vs baseline: 7.5100x; 1.0008x over previous
//
#include <hip/hip_runtime.h>
#include <hip/hip_bf16.h>
#include <stdint.h>

// TiedEmbeddingLinear: out[8192, 32768] = x[8192,4096] . W^T
// Pass 1: dequant NF4 W -> bf16 (ws). Pass 2: x fp32 -> bf16 (ws).
// Pass 3: 256x256 bf16 NT-GEMM, BK=64, frozen R5/R8 LDS geometry.
// R15: ONE-GATE TILE. A 3-deep (96 KB) + B 2-deep (64 KB). af(j+1) reads
// issued during tile j's Q1 chunks (legal: A(j+1) staged tile j-1, retired
// by end-of-(j-1) barrier), reusing the single af[8][2] register set in
// place (slot k reissued right after its last MFMA). bf read at top with
// split gate: LGKM(4) retires af(j)+bf_lo (the only real wait), LGKM(0)
// for bf_hi has a 32-MFMA lead. 4 gates/tile -> 1. R14's stagger removed (null).

#define M_DIM 8192
#define N_DIM 32768
#define K_DIM 4096
#define NT    64        // K / BK, BK = 64

typedef __attribute__((ext_vector_type(8))) short short8;
typedef __attribute__((ext_vector_type(4))) float f32x4;

__device__ __forceinline__ ushort f2bf(float f) {
    union { __hip_bfloat16 b; ushort u; } cv;
    cv.b = __float2bfloat16(f);
    return cv.u;
}

__device__ __forceinline__ void gload16(const ushort* g, ushort* l) {
    __builtin_amdgcn_global_load_lds(
        (const __attribute__((address_space(1))) unsigned int*)g,
        (__attribute__((address_space(3))) unsigned int*)l,
        16, 0, 0);
}

// asm LDS read (opaque to alias analysis; we own lgkmcnt)
__device__ __forceinline__ short8 ldsread128(const ushort* p) {
    short8 r;
    uint32_t a = (uint32_t)(uintptr_t)(const __attribute__((address_space(3))) ushort*)p;
    asm volatile("ds_read_b128 %0, %1" : "=v"(r) : "v"(a));
    return r;
}

#define BAR()     asm volatile("s_barrier" ::: "memory")
#define VMCNT0()  do { asm volatile("s_waitcnt vmcnt(0)" ::: "memory"); \
                       __builtin_amdgcn_sched_barrier(0); } while (0)
#define LGKM(N)   do { asm volatile("s_waitcnt lgkmcnt(" #N ")" ::: "memory"); \
                       __builtin_amdgcn_sched_barrier(0); } while (0)

// ---------------- pass 1: dequant W ----------------
__global__ __launch_bounds__(256) void dequant_w(
    const int* __restrict__ qw, const float* __restrict__ cb,
    uint32_t* __restrict__ wout)
{
    __shared__ uint32_t lut[256];
    const int tid = threadIdx.x;
    {
        const uint32_t h = f2bf(cb[(tid >> 4) & 15]);   // high nibble -> even d
        const uint32_t l = f2bf(cb[tid & 15]);          // low nibble  -> odd d
        lut[tid] = h | (l << 16);
    }
    __syncthreads();

    const size_t base = (size_t)blockIdx.x * 256 + tid;
    const int4* q4 = (const int4*)qw;
    uint4* w4 = (uint4*)wout;
    #pragma unroll
    for (int it = 0; it < 16; ++it) {
        const size_t idx = base + (size_t)it * (4096 * 256);
        const int4 q = q4[idx];
        uint4 w;
        w.x = lut[q.x & 255]; w.y = lut[q.y & 255];
        w.z = lut[q.z & 255]; w.w = lut[q.w & 255];
        w4[idx] = w;
    }
}

// ---------------- pass 2: x fp32 -> bf16 ----------------
__global__ __launch_bounds__(256) void conv_x(
    const float* __restrict__ x, ushort* __restrict__ xb)
{
    const size_t base = (size_t)blockIdx.x * 256 + threadIdx.x;
    #pragma unroll
    for (int it = 0; it < 8; ++it) {
        const size_t idx = (base + (size_t)it * (2048 * 256)) * 8;
        const float4 a = *(const float4*)(x + idx);
        const float4 b = *(const float4*)(x + idx + 4);
        short8 o;
        o[0] = f2bf(a.x); o[1] = f2bf(a.y); o[2] = f2bf(a.z); o[3] = f2bf(a.w);
        o[4] = f2bf(b.x); o[5] = f2bf(b.y); o[6] = f2bf(b.z); o[7] = f2bf(b.w);
        *(short8*)(xb + idx) = o;
    }
}

// ---------------- pass 3: 256^2 bf16 NT-GEMM, one-gate A3/B2 pipeline -------
__global__ __launch_bounds__(512, 2) void gemm_p5(
    const ushort* __restrict__ xb, const ushort* __restrict__ wb,
    const float* __restrict__ absmax, float* __restrict__ out)
{
    __shared__ ushort smA[3 * 16384];   // 96 KiB: A 3-deep
    __shared__ ushort smB[2 * 16384];   // 64 KiB: B 2-deep

    const int tid  = threadIdx.x;
    const int lane = tid & 63;
    const int wv   = tid >> 6;      // 0..7
    const int wm   = wv >> 2;       // 0..1  (128-row block)
    const int wn   = wv & 3;        // 0..3  (64-col block)

    const int bid = blockIdx.x;
    const int gm0 = (bid & 31) << 8;    // m fast: B panels shared, A L3-resident
    const int gn0 = (bid >> 5) << 8;

    // staging (R8 exact): lane -> (row l8, swizzled source granule)
    const int l8    = lane >> 3;
    const int sgran = (lane & 7) ^ l8;

    const ushort* aSrc = xb + (size_t)(gm0 + wv * 16 + l8) * K_DIM + sgran * 8;
    const ushort* bSrc = wb + (size_t)(gn0 + wv * 16 + l8) * K_DIM + sgran * 8;

    const int lr  = lane & 15;
    const int g   = lane >> 4;
    const int lr7 = lane & 7;

    f32x4  acc[8][4] = {};
    short8 af[8][2];    // single set: consumed per-tile, reissued in place
    short8 bf[4][2];    // single set: read at tile top

    #define LDF(P, ROW, S) \
        ldsread128((P) + ((ROW) + lr) * 64 + ((((S) * 4 + g) ^ lr7) * 8))

    #define STAGE(SRC, DST, KT) do { \
        gload16((SRC) + (size_t)(KT) * 64,                     (DST) + wv * 1024); \
        gload16((SRC) + (size_t)(KT) * 64 + (size_t)8 * K_DIM, (DST) + wv * 1024 + 512); \
    } while (0)
    #define STAGE_T(SRC, DSTBASE, KT) do { \
        STAGE(SRC, DSTBASE, KT); \
        STAGE(SRC + (size_t)128 * K_DIM, (DSTBASE) + 8192, KT); \
    } while (0)

    // Q0: all m x n0-1, 32 MFMA (needs bf_lo + full af set)
    #define MF_Q0() do { \
        __builtin_amdgcn_s_setprio(1); \
        _Pragma("unroll") \
        for (int s = 0; s < 2; ++s) \
            _Pragma("unroll") \
            for (int m = 0; m < 8; ++m) \
                _Pragma("unroll") \
                for (int n = 0; n < 2; ++n) \
                    acc[m][n] = __builtin_amdgcn_mfma_f32_16x16x32_bf16( \
                        af[m][s], bf[n][s], acc[m][n], 0, 0, 0); \
        __builtin_amdgcn_s_setprio(0); \
    } while (0)

    // Q1 chunk K: m-pair K x n2-3, 8 MFMA (last use of af pair K)
    #define MF8(K) do { \
        __builtin_amdgcn_s_setprio(1); \
        _Pragma("unroll") \
        for (int s = 0; s < 2; ++s) \
            _Pragma("unroll") \
            for (int m2 = 0; m2 < 2; ++m2) \
                _Pragma("unroll") \
                for (int n = 2; n < 4; ++n) \
                    acc[2 * (K) + m2][n] = __builtin_amdgcn_mfma_f32_16x16x32_bf16( \
                        af[2 * (K) + m2][s], bf[n][s], acc[2 * (K) + m2][n], 0, 0, 0); \
        __builtin_amdgcn_s_setprio(0); \
    } while (0)

    // reissue af pair K with tile j+1's fragments (buf a1; legal since A(j+1)
    // staged tile j-1 and retired by the end-of-(j-1) barrier)
    #define RD_P(K) do { \
        const ushort* _An = (const ushort*)smA + a1; \
        af[2 * (K)][0]     = LDF(_An, wm * 128 + (2 * (K)) * 16,     0); \
        af[2 * (K)][1]     = LDF(_An, wm * 128 + (2 * (K)) * 16,     1); \
        af[2 * (K) + 1][0] = LDF(_An, wm * 128 + (2 * (K) + 1) * 16, 0); \
        af[2 * (K) + 1][1] = LDF(_An, wm * 128 + (2 * (K) + 1) * 16, 1); \
    } while (0)

    // Tile j. Entry FIFO: [af(j) 16 (issued tile j-1, mostly retired)].
    // bf issue (lo first) -> stages -> LGKM(4): retire af(j)+bf_lo, keep
    // bf_hi -> Q0 -> LGKM(0) (bf_hi, ~free) -> 4x {8 MFMA; reissue af pair}
    // -> VMCNT0 -> BAR. Exit FIFO: [af(j+1) 16].
    #define TILE(J, BBCUR, BBNXT) do { \
        const ushort* _Bb = (const ushort*)smB + (BBCUR); \
        bf[0][0] = LDF(_Bb, wn * 64 + 0,  0); bf[0][1] = LDF(_Bb, wn * 64 + 0,  1); \
        bf[1][0] = LDF(_Bb, wn * 64 + 16, 0); bf[1][1] = LDF(_Bb, wn * 64 + 16, 1); \
        bf[2][0] = LDF(_Bb, wn * 64 + 32, 0); bf[2][1] = LDF(_Bb, wn * 64 + 32, 1); \
        bf[3][0] = LDF(_Bb, wn * 64 + 48, 0); bf[3][1] = LDF(_Bb, wn * 64 + 48, 1); \
        STAGE_T(aSrc, (ushort*)smA + a2,      (((J) + 2) & (NT - 1))); \
        STAGE_T(bSrc, (ushort*)smB + (BBNXT), (((J) + 1) & (NT - 1))); \
        LGKM(4); \
        MF_Q0(); \
        LGKM(0); \
        MF8(0); RD_P(0); \
        MF8(1); RD_P(1); \
        MF8(2); RD_P(2); \
        MF8(3); RD_P(3); \
        VMCNT0(); \
        BAR(); \
        int _t = a0; a0 = a1; a1 = a2; a2 = _t; \
    } while (0)

    int a0 = 0, a1 = 16384, a2 = 32768;   // bufs of A(j), A(j+1), A(j+2)

    // ---- prologue: stage A(0)->b0, A(1)->b1, B(0)->bb0; pre-read af(0) ----
    STAGE_T(aSrc, (ushort*)smA, 0);
    STAGE_T(aSrc, (ushort*)smA + 16384, 1);
    STAGE_T(bSrc, (ushort*)smB, 0);
    VMCNT0();
    BAR();
    #pragma unroll
    for (int m = 0; m < 8; ++m) {
        af[m][0] = LDF((const ushort*)smA, wm * 128 + m * 16, 0);
        af[m][1] = LDF((const ushort*)smA, wm * 128 + m * 16, 1);
    }
    // FIFO: [af(0) 16] — matches tile entry state.

    for (int j = 0; j < NT; j += 2) {
        TILE(j,     0,     16384);
        TILE(j + 1, 16384, 0);
    }
    LGKM(0);   // retire trailing af reads before epilogue reuses their regs

    // ---- epilogue: absmax[col] scale, plain fp32 stores ----
    float am[4];
    #pragma unroll
    for (int n = 0; n < 4; ++n)
        am[n] = absmax[gn0 + wn * 64 + n * 16 + lr];

    const int row0 = gm0 + wm * 128 + g * 4;
    const int col0 = gn0 + wn * 64 + lr;
    #pragma unroll
    for (int m = 0; m < 8; ++m) {
        #pragma unroll
        for (int n = 0; n < 4; ++n) {
            #pragma unroll
            for (int r = 0; r < 4; ++r) {
                out[(size_t)(row0 + m * 16 + r) * N_DIM + col0 + n * 16] =
                    acc[m][n][r] * am[n];
            }
        }
    }
}

extern "C" void kernel_launch(void* const* d_in, const int* in_sizes, int n_in,
                              void* d_out, int out_size, void* d_ws, size_t ws_size,
                              hipStream_t stream) {
    const float* x      = (const float*)d_in[0];
    const int*   qw     = (const int*)d_in[1];
    const float* absmax = (const float*)d_in[2];
    const float* cb     = (const float*)d_in[3];
    float* out = (float*)d_out;

    const size_t W_BYTES = (size_t)N_DIM * K_DIM * 2;   // 256 MiB bf16 W
    uint32_t* wq  = (uint32_t*)d_ws;
    ushort*   xbf = (ushort*)((char*)d_ws + W_BYTES);

    dequant_w<<<4096, 256, 0, stream>>>(qw, cb, wq);
    conv_x<<<2048, 256, 0, stream>>>(x, xbf);
    gemm_p5<<<dim3((M_DIM / 256) * (N_DIM / 256)), dim3(512), 0, stream>>>(
        xbf, (const ushort*)wq, absmax, out);
}